// Round 1
// baseline (9903.823 us; speedup 1.0000x reference)
//
#include <hip/hip_runtime.h>
#include <hip/hip_bf16.h>

// Problem constants (reference: B=2, L=2048, D=4096, H=32, HKV=8, HD=128)
#define BB 2
#define LL 2048
#define DD 4096
#define HH 32
#define HKV 8
#define HDIM 128
#define MROWS (BB*LL)          // 4096

// ---------------------------------------------------------------------------
// fp32 NT GEMM: C[M,N] = A[M,K] * B[N,K]^T   (A,B,C row-major)
// 128x128 tile, BK=16, 256 threads, 8x8 micro-tile (split 4+4 to keep LDS
// read strides at 4 floats -> worst 2-way bank aliasing, which is free).
// ---------------------------------------------------------------------------
#define GBM 128
#define GBN 128
#define GBK 16

__global__ __launch_bounds__(256) void gemm_nt(
    const float* __restrict__ A, const float* __restrict__ B,
    float* __restrict__ C, int M, int N, int K) {
  __shared__ float As[GBK][GBM + 4];
  __shared__ float Bs[GBK][GBN + 4];
  const int tid = threadIdx.x;
  const int tc = tid & 15;          // 0..15 -> cols
  const int tr = tid >> 4;          // 0..15 -> rows
  const int brow = blockIdx.y * GBM;
  const int bcol = blockIdx.x * GBN;

  float acc[8][8] = {};

  for (int k0 = 0; k0 < K; k0 += GBK) {
    // Stage A,B tiles: 128x16 floats = 512 float4 each; 256 threads -> 2 each.
#pragma unroll
    for (int ld = 0; ld < 2; ++ld) {
      int f = tid + ld * 256;                 // float4 slot 0..511
      int m = f >> 2;                         // row in tile 0..127
      int k4 = (f & 3) << 2;                  // k offset 0,4,8,12
      float4 va = *(const float4*)&A[(size_t)(brow + m) * K + k0 + k4];
      As[k4 + 0][m] = va.x; As[k4 + 1][m] = va.y;
      As[k4 + 2][m] = va.z; As[k4 + 3][m] = va.w;
      float4 vb = *(const float4*)&B[(size_t)(bcol + m) * K + k0 + k4];
      Bs[k4 + 0][m] = vb.x; Bs[k4 + 1][m] = vb.y;
      Bs[k4 + 2][m] = vb.z; Bs[k4 + 3][m] = vb.w;
    }
    __syncthreads();

#pragma unroll
    for (int kk = 0; kk < GBK; ++kk) {
      float a[8], b[8];
#pragma unroll
      for (int i = 0; i < 4; ++i) {
        a[i]     = As[kk][tr * 4 + i];
        a[i + 4] = As[kk][64 + tr * 4 + i];
        b[i]     = Bs[kk][tc * 4 + i];
        b[i + 4] = Bs[kk][64 + tc * 4 + i];
      }
#pragma unroll
      for (int i = 0; i < 8; ++i)
#pragma unroll
        for (int j = 0; j < 8; ++j)
          acc[i][j] += a[i] * b[j];
    }
    __syncthreads();
  }

#pragma unroll
  for (int i = 0; i < 8; ++i) {
    int r = brow + ((i < 4) ? (tr * 4 + i) : (64 + tr * 4 + (i - 4)));
#pragma unroll
    for (int j = 0; j < 8; ++j) {
      int c = bcol + ((j < 4) ? (tc * 4 + j) : (64 + tc * 4 + (j - 4)));
      C[(size_t)r * N + c] = acc[i][j];
    }
  }
}

// ---------------------------------------------------------------------------
// RoPE: in-place on xq [M, H*HD] and xk [M, HKV*HD].
// Pair p within a head: (2i, 2i+1), i in [0,64); cos/sin indexed [l, i].
// ---------------------------------------------------------------------------
__global__ __launch_bounds__(256) void rope_kernel(
    float* __restrict__ q, float* __restrict__ k,
    const float* __restrict__ cosp, const float* __restrict__ sinp) {
  const int row = blockIdx.x;          // b*L + l
  const int l = row % LL;
  const int NPQ = HH * HDIM / 2;       // 2048 q pairs per row
  const int NPK = HKV * HDIM / 2;      // 512 k pairs per row
  for (int p = threadIdx.x; p < NPQ + NPK; p += blockDim.x) {
    bool isq = p < NPQ;
    float* base = isq ? (q + (size_t)row * (HH * HDIM))
                      : (k + (size_t)row * (HKV * HDIM));
    int pp = isq ? p : (p - NPQ);
    int i = pp & (HDIM / 2 - 1);       // freq index 0..63
    float c = cosp[l * (HDIM / 2) + i];
    float s = sinp[l * (HDIM / 2) + i];
    float tr = base[2 * pp], ti = base[2 * pp + 1];
    base[2 * pp]     = tr * c - ti * s;
    base[2 * pp + 1] = tr * s + ti * c;
  }
}

// ---------------------------------------------------------------------------
// Flash-style causal GQA attention, fp32.
// Grid: (L/QT, B*H). Block: 256 threads.
// Thread t: query row qr = t>>2 (64 rows/block), head-dim quarter part = t&3
// (32 dims). Scores reduced across the 4 lanes of a query via shfl_xor(1,2).
// Online softmax state (m,l) kept redundantly in all 4 lanes.
// ---------------------------------------------------------------------------
#define QT 64
#define KT 32

__global__ __launch_bounds__(256) void attn_kernel(
    const float* __restrict__ Q, const float* __restrict__ Kc,
    const float* __restrict__ Vc, float* __restrict__ O) {
  __shared__ float Ks[KT][HDIM];   // 16 KB
  __shared__ float Vs[KT][HDIM];   // 16 KB
  const int tid = threadIdx.x;
  const int qr = tid >> 2;
  const int part = tid & 3;
  const int qt = blockIdx.x;
  const int bh = blockIdx.y;
  const int b = bh / HH, h = bh % HH;
  const int kvh = h / (HH / HKV);
  const int qpos = qt * QT + qr;
  const size_t qrow = (size_t)(b * LL + qpos) * (HH * HDIM) + h * HDIM + part * 32;

  float qreg[32], o[32] = {};
#pragma unroll
  for (int i = 0; i < 8; ++i) {
    float4 v = *(const float4*)&Q[qrow + i * 4];
    qreg[i * 4] = v.x; qreg[i * 4 + 1] = v.y;
    qreg[i * 4 + 2] = v.z; qreg[i * 4 + 3] = v.w;
  }

  float m = -1e30f, lsum = 0.f;
  const float scale = 0.08838834764831845f;  // 1/sqrt(128)
  const int kmax = qt * QT + QT;             // causal upper bound for block

  for (int k0 = 0; k0 < kmax; k0 += KT) {
    // Stage K,V tile: KT*HD = 4096 floats = 1024 float4; 256 thr -> 4 each.
#pragma unroll
    for (int ld = 0; ld < 4; ++ld) {
      int f = tid + ld * 256;
      int row = f >> 5, col4 = (f & 31) << 2;
      size_t g = (size_t)(b * LL + k0 + row) * (HKV * HDIM) + kvh * HDIM + col4;
      *(float4*)&Ks[row][col4] = *(const float4*)&Kc[g];
      *(float4*)&Vs[row][col4] = *(const float4*)&Vc[g];
    }
    __syncthreads();

    float s[KT];
#pragma unroll
    for (int j = 0; j < KT; ++j) {
      float p = 0.f;
#pragma unroll
      for (int d = 0; d < 32; ++d)
        p += qreg[d] * Ks[j][part * 32 + d];
      p += __shfl_xor(p, 1);
      p += __shfl_xor(p, 2);
      int kpos = k0 + j;
      s[j] = (kpos <= qpos) ? p * scale : -1e30f;
    }

    float mnew = m;
#pragma unroll
    for (int j = 0; j < KT; ++j) mnew = fmaxf(mnew, s[j]);
    float corr = __expf(m - mnew);
    lsum *= corr;
#pragma unroll
    for (int d = 0; d < 32; ++d) o[d] *= corr;
#pragma unroll
    for (int j = 0; j < KT; ++j) {
      float p = __expf(s[j] - mnew);
      lsum += p;
#pragma unroll
      for (int d = 0; d < 32; ++d)
        o[d] += p * Vs[j][part * 32 + d];
    }
    m = mnew;
    __syncthreads();
  }

  float inv = 1.f / lsum;
#pragma unroll
  for (int i = 0; i < 8; ++i) {
    float4 v = { o[i * 4] * inv, o[i * 4 + 1] * inv,
                 o[i * 4 + 2] * inv, o[i * 4 + 3] * inv };
    *(float4*)&O[qrow + i * 4] = v;
  }
}

// ---------------------------------------------------------------------------
// Launch: xq = x@wq^T ; xk = x@wk^T ; xv = x@wv^T ; RoPE(q,k) ;
//         attn = flash(xq,xk,xv) ; out = attn@wo^T
// Workspace layout (fp32): xq 64MB | xk 16MB | xv 16MB | attn 64MB = 160MB.
// ---------------------------------------------------------------------------
extern "C" void kernel_launch(void* const* d_in, const int* in_sizes, int n_in,
                              void* d_out, int out_size, void* d_ws, size_t ws_size,
                              hipStream_t stream) {
  const float* x    = (const float*)d_in[0];
  const float* wq   = (const float*)d_in[1];
  const float* wk   = (const float*)d_in[2];
  const float* wv   = (const float*)d_in[3];
  const float* wo   = (const float*)d_in[4];
  const float* cosp = (const float*)d_in[5];
  const float* sinp = (const float*)d_in[6];
  // d_in[7] = mask: causality is applied analytically in attn_kernel.
  float* out = (float*)d_out;

  float* xq   = (float*)d_ws;                       // [4096, 4096]
  float* xk   = xq + (size_t)MROWS * DD;            // [4096, 1024]
  float* xv   = xk + (size_t)MROWS * (HKV * HDIM);  // [4096, 1024]
  float* attn = xv + (size_t)MROWS * (HKV * HDIM);  // [4096, 4096]

  dim3 blk(256);
  // QKV projections
  gemm_nt<<<dim3(DD / GBN, MROWS / GBM), blk, 0, stream>>>(x, wq, xq, MROWS, DD, DD);
  gemm_nt<<<dim3((HKV * HDIM) / GBN, MROWS / GBM), blk, 0, stream>>>(x, wk, xk, MROWS, HKV * HDIM, DD);
  gemm_nt<<<dim3((HKV * HDIM) / GBN, MROWS / GBM), blk, 0, stream>>>(x, wv, xv, MROWS, HKV * HDIM, DD);
  // RoPE in-place on xq, xk
  rope_kernel<<<dim3(MROWS), blk, 0, stream>>>(xq, xk, cosp, sinp);
  // Causal GQA attention
  attn_kernel<<<dim3(LL / QT, BB * HH), blk, 0, stream>>>(xq, xk, xv, attn);
  // Output projection
  gemm_nt<<<dim3(DD / GBN, MROWS / GBM), blk, 0, stream>>>(attn, wo, out, MROWS, DD, DD);
}

// Round 6
// 1525.372 us; speedup vs baseline: 6.4927x; 6.4927x over previous
//
#include <hip/hip_runtime.h>

// Problem constants (B=2, L=2048, D=4096, H=32, HKV=8, HD=128)
#define BB 2
#define LL 2048
#define DD 4096
#define HH 32
#define NKV 8
#define HDIM 128
#define MROWS (BB*LL)   // 4096

typedef __attribute__((ext_vector_type(8))) short bf16x8;     // MFMA A/B operand
typedef __attribute__((ext_vector_type(8))) unsigned short u16x8;
typedef __attribute__((ext_vector_type(4))) unsigned short u16x4;
typedef __attribute__((ext_vector_type(4))) float f32x4;       // MFMA C/D

#define MFMA16(a, b, c) __builtin_amdgcn_mfma_f32_16x16x32_bf16(a, b, c, 0, 0, 0)

__device__ __forceinline__ unsigned short f2bf(float x) {      // RNE f32->bf16
  union { float f; unsigned u; } v; v.f = x;
  unsigned r = v.u + 0x7FFF + ((v.u >> 16) & 1);
  return (unsigned short)(r >> 16);
}
__device__ __forceinline__ float bf2f(unsigned short h) {
  union { unsigned u; float f; } v; v.u = ((unsigned)h) << 16; return v.f;
}
__device__ __forceinline__ unsigned packbf2(float lo, float hi) {
  return ((unsigned)f2bf(hi) << 16) | (unsigned)f2bf(lo);
}
__device__ __forceinline__ void gload_lds16(const void* g, void* l) {
  __builtin_amdgcn_global_load_lds(
      (const __attribute__((address_space(1))) unsigned int*)g,
      (__attribute__((address_space(3))) unsigned int*)l, 16, 0, 0);
}

// ---------------------------------------------------------------------------
// cast fp32 -> bf16 (x must be bf16 for global_load_lds GEMM staging)
// ---------------------------------------------------------------------------
__global__ __launch_bounds__(256) void cast_f32_bf16(
    const float* __restrict__ in, unsigned short* __restrict__ out, int n) {
  int stride = gridDim.x * blockDim.x * 4;
  for (int i = (blockIdx.x * blockDim.x + threadIdx.x) * 4; i < n; i += stride) {
    float4 v = *(const float4*)&in[i];
    u16x4 u;
    u[0] = f2bf(v.x); u[1] = f2bf(v.y); u[2] = f2bf(v.z); u[3] = f2bf(v.w);
    *(u16x4*)&out[i] = u;
  }
}

// ---------------------------------------------------------------------------
// bf16 MFMA NT GEMM: C[M,N] = A[M,K](bf16) * B[N,K](f32->bf16)^T
// 128x128 tile, BK=64, 4 waves (2x2), 4x4 MFMA frags per wave.
// A: global_load_lds w16, source pre-XOR-swizzled (slot ^ (row&7)).
// B: reg-staged f32->bf16, ds_write_b128 to swizzled slot.
// ---------------------------------------------------------------------------
template <bool OUTBF>
__global__ __launch_bounds__(256) void gemm_bt(
    const unsigned short* __restrict__ A, const float* __restrict__ B,
    void* __restrict__ Cv, int M, int N, int K) {
  __shared__ unsigned short As[128 * 64];  // [row][64 k] 128B rows, swizzled
  __shared__ unsigned short Bs[128 * 64];
  const int tid = threadIdx.x;
  const int lane = tid & 63, w = tid >> 6;
  const int l15 = lane & 15, lg = lane >> 4;
  const int wr = w >> 1, wc = w & 1;
  const int brow = blockIdx.y * 128, bcol = blockIdx.x * 128;

  f32x4 acc[4][4];
#pragma unroll
  for (int m = 0; m < 4; ++m)
#pragma unroll
    for (int n = 0; n < 4; ++n)
#pragma unroll
      for (int j = 0; j < 4; ++j) acc[m][n][j] = 0.f;

  for (int k0 = 0; k0 < K; k0 += 64) {
    // A tile: 128x64 bf16 = 1024 x 16B slots, linear dest, swizzled source.
#pragma unroll
    for (int i = 0; i < 4; ++i) {
      int idx = i * 256 + tid;
      int row = idx >> 3, s = idx & 7;
      gload_lds16(&A[(size_t)(brow + row) * K + k0 + ((s ^ (row & 7)) * 8)],
                  &As[idx * 8]);
    }
    // B tile: reg-stage fp32 -> bf16, write phys slot s holding logical col.
#pragma unroll
    for (int i = 0; i < 4; ++i) {
      int f = i * 256 + tid;
      int row = f >> 3, s = f & 7;
      const float* src = &B[(size_t)(bcol + row) * K + k0 + ((s ^ (row & 7)) * 8)];
      float4 f0 = *(const float4*)src;
      float4 f1 = *(const float4*)(src + 4);
      u16x8 u;
      u[0] = f2bf(f0.x); u[1] = f2bf(f0.y); u[2] = f2bf(f0.z); u[3] = f2bf(f0.w);
      u[4] = f2bf(f1.x); u[5] = f2bf(f1.y); u[6] = f2bf(f1.z); u[7] = f2bf(f1.w);
      *(u16x8*)&Bs[f * 8] = u;
    }
    __syncthreads();
#pragma unroll
    for (int kk = 0; kk < 2; ++kk) {
      bf16x8 af[4], bfr[4];
      const int phys = (kk * 4 + lg) ^ (l15 & 7);
#pragma unroll
      for (int m = 0; m < 4; ++m) {
        int row = wr * 64 + m * 16 + l15;
        af[m] = *(const bf16x8*)&As[row * 64 + phys * 8];
      }
#pragma unroll
      for (int n = 0; n < 4; ++n) {
        int row = wc * 64 + n * 16 + l15;
        bfr[n] = *(const bf16x8*)&Bs[row * 64 + phys * 8];
      }
#pragma unroll
      for (int m = 0; m < 4; ++m)
#pragma unroll
        for (int n = 0; n < 4; ++n)
          acc[m][n] = MFMA16(af[m], bfr[n], acc[m][n]);
    }
    __syncthreads();
  }

#pragma unroll
  for (int m = 0; m < 4; ++m)
#pragma unroll
    for (int n = 0; n < 4; ++n)
#pragma unroll
      for (int j = 0; j < 4; ++j) {
        int r = brow + wr * 64 + m * 16 + lg * 4 + j;
        int c = bcol + wc * 64 + n * 16 + l15;
        if (OUTBF)
          ((unsigned short*)Cv)[(size_t)r * N + c] = f2bf(acc[m][n][j]);
        else
          ((float*)Cv)[(size_t)r * N + c] = acc[m][n][j];
      }
}

// ---------------------------------------------------------------------------
// RoPE in place on bf16 q [4096, 4096] and k [4096, 1024]; one u32 = one pair.
// ---------------------------------------------------------------------------
__global__ __launch_bounds__(256) void rope_bf16(
    unsigned* __restrict__ q, unsigned* __restrict__ k,
    const float* __restrict__ cosp, const float* __restrict__ sinp) {
  const int NQ = MROWS * (DD / 2);           // 8.39M q pairs
  const int NT = NQ + MROWS * (NKV * HDIM / 2);
  int stride = gridDim.x * blockDim.x;
  for (int p = blockIdx.x * blockDim.x + threadIdx.x; p < NT; p += stride) {
    bool isq = p < NQ;
    int pp = isq ? p : p - NQ;
    int row = isq ? (pp >> 11) : (pp >> 9);
    int hp  = isq ? (pp & 2047) : (pp & 511);
    int i = hp & 63, l = row & (LL - 1);
    float c = cosp[l * 64 + i], s = sinp[l * 64 + i];
    unsigned* ptr = isq ? (q + (size_t)row * 2048 + hp)
                        : (k + (size_t)row * 512 + hp);
    unsigned v = *ptr;
    float tr = bf2f((unsigned short)(v & 0xffff));
    float ti = bf2f((unsigned short)(v >> 16));
    *ptr = packbf2(tr * c - ti * s, tr * s + ti * c);
  }
}

// ---------------------------------------------------------------------------
// Flash causal GQA attention, bf16 MFMA.
// Grid (L/64, B*H), 4 waves; wave w owns 16 q rows. KV tile = 64 keys.
// Swapped QK^T: S^T = K*Q^T so lane column = q. Softmax via 2x shfl_xor.
// P repacked to PV B-frags via 16 shuffles. V transposed into LDS (swizzled).
// ---------------------------------------------------------------------------
__global__ __launch_bounds__(256) void attn_mfma(
    const unsigned short* __restrict__ Qb, const unsigned short* __restrict__ Kb,
    const unsigned short* __restrict__ Vb, unsigned short* __restrict__ Ob) {
  __shared__ unsigned short Ks[64 * 128];  // [key][dim] 256B rows, 16-slot swz
  __shared__ unsigned short Vt[128 * 64];  // [dim][key] 128B rows, 8-slot swz
  const int tid = threadIdx.x;
  const int lane = tid & 63, w = tid >> 6;
  const int l15 = lane & 15, lg = lane >> 4;
  const int qt = (int)gridDim.x - 1 - (int)blockIdx.x;  // heavy blocks first
  const int bh = blockIdx.y;
  const int b = bh >> 5, h = bh & 31, kvh = h >> 2;
  const int qrel = w * 16 + l15;
  const size_t qrow = (size_t)(b * LL + qt * 64 + qrel);

  bf16x8 qf[4];
#pragma unroll
  for (int c = 0; c < 4; ++c)
    qf[c] = *(const bf16x8*)&Qb[qrow * DD + h * HDIM + c * 32 + lg * 8];

  f32x4 oacc[8];
#pragma unroll
  for (int d = 0; d < 8; ++d)
#pragma unroll
    for (int j = 0; j < 4; ++j) oacc[d][j] = 0.f;
  float mrun = -1e30f, lrun = 0.f;
  const float scale = 0.08838834764831845f;  // 1/sqrt(128)

  for (int t0 = 0; t0 <= qt; ++t0) {
    const int k0 = t0 * 64;
    // K tile via global_load_lds (linear dest idx*16B, source pre-swizzled).
#pragma unroll
    for (int i = 0; i < 4; ++i) {
      int idx = i * 256 + tid;
      int krow = idx >> 4, slot = idx & 15;
      gload_lds16(&Kb[(size_t)(b * LL + k0 + krow) * (NKV * HDIM) + kvh * HDIM +
                      ((slot ^ (krow & 15)) * 8)],
                  &Ks[idx * 8]);
    }
    // V tile transposed: lane loads 8 dims of key==f&63, scatters to Vt.
#pragma unroll
    for (int i = 0; i < 4; ++i) {
      int f = i * 256 + tid;
      int key = f & 63, d0 = (f >> 6) * 8;
      u16x8 v = *(const u16x8*)&Vb[(size_t)(b * LL + k0 + key) * (NKV * HDIM) +
                                   kvh * HDIM + d0];
#pragma unroll
      for (int j = 0; j < 8; ++j) {
        int dim = d0 + j;
        Vt[dim * 64 + (((key >> 3) ^ (dim & 7)) * 8) + (key & 7)] = v[j];
      }
    }
    __syncthreads();

    // S^T[64key][16q] = K * Q^T
    f32x4 sa[4];
#pragma unroll
    for (int mb = 0; mb < 4; ++mb) {
#pragma unroll
      for (int j = 0; j < 4; ++j) sa[mb][j] = 0.f;
#pragma unroll
      for (int c = 0; c < 4; ++c) {
        int row = mb * 16 + l15;
        int phys = (c * 4 + lg) ^ l15;  // 16-slot swizzle
        bf16x8 kf = *(const bf16x8*)&Ks[row * 128 + phys * 8];
        sa[mb] = MFMA16(kf, qf[c], sa[mb]);
      }
    }

    // scale + causal mask (only boundary tile) -> in-place exp
    const bool boundary = (t0 == qt);
#pragma unroll
    for (int mb = 0; mb < 4; ++mb)
#pragma unroll
      for (int j = 0; j < 4; ++j) {
        float s = sa[mb][j] * scale;
        if (boundary && (mb * 16 + lg * 4 + j > qrel)) s = -1e30f;
        sa[mb][j] = s;
      }
    float vm = -1e30f;
#pragma unroll
    for (int mb = 0; mb < 4; ++mb)
#pragma unroll
      for (int j = 0; j < 4; ++j) vm = fmaxf(vm, sa[mb][j]);
    vm = fmaxf(vm, __shfl_xor(vm, 16));
    vm = fmaxf(vm, __shfl_xor(vm, 32));
    float mnew = fmaxf(mrun, vm);
    float corr = __expf(mrun - mnew);
    float psum = 0.f;
#pragma unroll
    for (int mb = 0; mb < 4; ++mb)
#pragma unroll
      for (int j = 0; j < 4; ++j) {
        float p = __expf(sa[mb][j] - mnew);
        sa[mb][j] = p;
        psum += p;
      }
    psum += __shfl_xor(psum, 16);
    psum += __shfl_xor(psum, 32);
    lrun = lrun * corr + psum;
    mrun = mnew;
#pragma unroll
    for (int d = 0; d < 8; ++d)
#pragma unroll
      for (int j = 0; j < 4; ++j) oacc[d][j] *= corr;

    // pack P to bf16 pairs: pk[mb][0]=(j0,j1), pk[mb][1]=(j2,j3)
    unsigned pk[4][2];
#pragma unroll
    for (int mb = 0; mb < 4; ++mb) {
      pk[mb][0] = packbf2(sa[mb][0], sa[mb][1]);
      pk[mb][1] = packbf2(sa[mb][2], sa[mb][3]);
    }

    // PV: O^T[128dim][16q] += V^T * P^T  (two K=32 halves)
#pragma unroll
    for (int kh = 0; kh < 2; ++kh) {
      unsigned pbu[4];
#pragma unroll
      for (int r = 0; r < 4; ++r) {
        int srcl = l15 + 16 * ((lg & 1) * 2 + (r >> 1));
        unsigned va = (unsigned)__shfl((int)pk[2 * kh][r & 1], srcl);
        unsigned vb = (unsigned)__shfl((int)pk[2 * kh + 1][r & 1], srcl);
        pbu[r] = (lane & 32) ? vb : va;
      }
      bf16x8 pb;
#pragma unroll
      for (int r = 0; r < 4; ++r) {
        pb[2 * r]     = (short)(pbu[r] & 0xffff);
        pb[2 * r + 1] = (short)(pbu[r] >> 16);
      }
      const int phys = ((kh * 4 + lg) ^ (l15 & 7));
#pragma unroll
      for (int mbd = 0; mbd < 8; ++mbd) {
        int row = mbd * 16 + l15;
        bf16x8 vf = *(const bf16x8*)&Vt[row * 64 + phys * 8];
        oacc[mbd] = MFMA16(vf, pb, oacc[mbd]);
      }
    }
    __syncthreads();
  }

  // epilogue: O^T frag (dim=mbd*16+lg*4+j, q=l15) -> bf16 rows of attn buffer
  float inv = 1.f / lrun;
#pragma unroll
  for (int mbd = 0; mbd < 8; ++mbd)
#pragma unroll
    for (int j = 0; j < 4; j += 2) {
      int dim = mbd * 16 + lg * 4 + j;
      unsigned pk2 = packbf2(oacc[mbd][j] * inv, oacc[mbd][j + 1] * inv);
      *(unsigned*)&Ob[qrow * DD + h * HDIM + dim] = pk2;
    }
}

// ---------------------------------------------------------------------------
// Launch graph: cast(x) ; q,k,v GEMMs ; rope ; attn ; out GEMM
// ws (bytes): xb 32M | qbf 32M | kbf 8M | vbf 8M | attnbf 32M = 112 MB
// ---------------------------------------------------------------------------
extern "C" void kernel_launch(void* const* d_in, const int* in_sizes, int n_in,
                              void* d_out, int out_size, void* d_ws, size_t ws_size,
                              hipStream_t stream) {
  const float* x    = (const float*)d_in[0];
  const float* wq   = (const float*)d_in[1];
  const float* wk   = (const float*)d_in[2];
  const float* wv   = (const float*)d_in[3];
  const float* wo   = (const float*)d_in[4];
  const float* cosp = (const float*)d_in[5];
  const float* sinp = (const float*)d_in[6];
  float* out = (float*)d_out;

  unsigned short* xb     = (unsigned short*)d_ws;
  unsigned short* qbf    = xb + (size_t)MROWS * DD;
  unsigned short* kbf    = qbf + (size_t)MROWS * DD;
  unsigned short* vbf    = kbf + (size_t)MROWS * (NKV * HDIM);
  unsigned short* attnbf = vbf + (size_t)MROWS * (NKV * HDIM);

  dim3 blk(256);
  cast_f32_bf16<<<4096, blk, 0, stream>>>(x, xb, MROWS * DD);
  gemm_bt<true><<<dim3(DD / 128, MROWS / 128), blk, 0, stream>>>(
      xb, wq, qbf, MROWS, DD, DD);
  gemm_bt<true><<<dim3((NKV * HDIM) / 128, MROWS / 128), blk, 0, stream>>>(
      xb, wk, kbf, MROWS, NKV * HDIM, DD);
  gemm_bt<true><<<dim3((NKV * HDIM) / 128, MROWS / 128), blk, 0, stream>>>(
      xb, wv, vbf, MROWS, NKV * HDIM, DD);
  rope_bf16<<<8192, blk, 0, stream>>>((unsigned*)qbf, (unsigned*)kbf, cosp, sinp);
  attn_mfma<<<dim3(LL / 64, BB * HH), blk, 0, stream>>>(qbf, kbf, vbf, attnbf);
  gemm_bt<false><<<dim3(DD / 128, MROWS / 128), blk, 0, stream>>>(
      attnbf, wo, out, MROWS, DD, DD);
}

// Round 7
// 1229.735 us; speedup vs baseline: 8.0536x; 1.2404x over previous
//
#include <hip/hip_runtime.h>

// Problem constants (B=2, L=2048, D=4096, H=32, HKV=8, HD=128)
#define BB 2
#define LL 2048
#define DD 4096
#define HH 32
#define NKV 8
#define HDIM 128
#define MROWS (BB*LL)   // 4096

typedef __attribute__((ext_vector_type(8))) short bf16x8;     // MFMA A/B operand
typedef __attribute__((ext_vector_type(8))) unsigned short u16x8;
typedef __attribute__((ext_vector_type(4))) unsigned short u16x4;
typedef __attribute__((ext_vector_type(4))) float f32x4;       // MFMA C/D

#define MFMA16(a, b, c) __builtin_amdgcn_mfma_f32_16x16x32_bf16(a, b, c, 0, 0, 0)

__device__ __forceinline__ unsigned short f2bf(float x) {      // RNE f32->bf16
  union { float f; unsigned u; } v; v.f = x;
  unsigned r = v.u + 0x7FFF + ((v.u >> 16) & 1);
  return (unsigned short)(r >> 16);
}
__device__ __forceinline__ float bf2f(unsigned short h) {
  union { unsigned u; float f; } v; v.u = ((unsigned)h) << 16; return v.f;
}
__device__ __forceinline__ unsigned packbf2(float lo, float hi) {
  return ((unsigned)f2bf(hi) << 16) | (unsigned)f2bf(lo);
}
__device__ __forceinline__ void gload_lds16(const void* g, void* l) {
  __builtin_amdgcn_global_load_lds(
      (const __attribute__((address_space(1))) unsigned int*)g,
      (__attribute__((address_space(3))) unsigned int*)l, 16, 0, 0);
}

// ---------------------------------------------------------------------------
// cast fp32 -> bf16 (x must be bf16 for global_load_lds GEMM staging)
// ---------------------------------------------------------------------------
__global__ __launch_bounds__(256) void cast_f32_bf16(
    const float* __restrict__ in, unsigned short* __restrict__ out, int n) {
  int stride = gridDim.x * blockDim.x * 4;
  for (int i = (blockIdx.x * blockDim.x + threadIdx.x) * 4; i < n; i += stride) {
    float4 v = *(const float4*)&in[i];
    u16x4 u;
    u[0] = f2bf(v.x); u[1] = f2bf(v.y); u[2] = f2bf(v.z); u[3] = f2bf(v.w);
    *(u16x4*)&out[i] = u;
  }
}

// ---------------------------------------------------------------------------
// bf16 MFMA NT GEMM: C[M,N] = A[M,K](bf16) * B[N,K](f32->bf16)^T
// 128x128 tile, BK=64, 4 waves (2x2), 4x4 MFMA frags per wave. (unchanged)
// ---------------------------------------------------------------------------
template <bool OUTBF>
__global__ __launch_bounds__(256) void gemm_bt(
    const unsigned short* __restrict__ A, const float* __restrict__ B,
    void* __restrict__ Cv, int M, int N, int K) {
  __shared__ unsigned short As[128 * 64];  // [row][64 k] 128B rows, swizzled
  __shared__ unsigned short Bs[128 * 64];
  const int tid = threadIdx.x;
  const int lane = tid & 63, w = tid >> 6;
  const int l15 = lane & 15, lg = lane >> 4;
  const int wr = w >> 1, wc = w & 1;
  const int brow = blockIdx.y * 128, bcol = blockIdx.x * 128;

  f32x4 acc[4][4];
#pragma unroll
  for (int m = 0; m < 4; ++m)
#pragma unroll
    for (int n = 0; n < 4; ++n)
#pragma unroll
      for (int j = 0; j < 4; ++j) acc[m][n][j] = 0.f;

  for (int k0 = 0; k0 < K; k0 += 64) {
    // A tile: 128x64 bf16 = 1024 x 16B slots, linear dest, swizzled source.
#pragma unroll
    for (int i = 0; i < 4; ++i) {
      int idx = i * 256 + tid;
      int row = idx >> 3, s = idx & 7;
      gload_lds16(&A[(size_t)(brow + row) * K + k0 + ((s ^ (row & 7)) * 8)],
                  &As[idx * 8]);
    }
    // B tile: reg-stage fp32 -> bf16, write phys slot s holding logical col.
#pragma unroll
    for (int i = 0; i < 4; ++i) {
      int f = i * 256 + tid;
      int row = f >> 3, s = f & 7;
      const float* src = &B[(size_t)(bcol + row) * K + k0 + ((s ^ (row & 7)) * 8)];
      float4 f0 = *(const float4*)src;
      float4 f1 = *(const float4*)(src + 4);
      u16x8 u;
      u[0] = f2bf(f0.x); u[1] = f2bf(f0.y); u[2] = f2bf(f0.z); u[3] = f2bf(f0.w);
      u[4] = f2bf(f1.x); u[5] = f2bf(f1.y); u[6] = f2bf(f1.z); u[7] = f2bf(f1.w);
      *(u16x8*)&Bs[f * 8] = u;
    }
    __syncthreads();
#pragma unroll
    for (int kk = 0; kk < 2; ++kk) {
      bf16x8 af[4], bfr[4];
      const int phys = (kk * 4 + lg) ^ (l15 & 7);
#pragma unroll
      for (int m = 0; m < 4; ++m) {
        int row = wr * 64 + m * 16 + l15;
        af[m] = *(const bf16x8*)&As[row * 64 + phys * 8];
      }
#pragma unroll
      for (int n = 0; n < 4; ++n) {
        int row = wc * 64 + n * 16 + l15;
        bfr[n] = *(const bf16x8*)&Bs[row * 64 + phys * 8];
      }
#pragma unroll
      for (int m = 0; m < 4; ++m)
#pragma unroll
        for (int n = 0; n < 4; ++n)
          acc[m][n] = MFMA16(af[m], bfr[n], acc[m][n]);
    }
    __syncthreads();
  }

#pragma unroll
  for (int m = 0; m < 4; ++m)
#pragma unroll
    for (int n = 0; n < 4; ++n)
#pragma unroll
      for (int j = 0; j < 4; ++j) {
        int r = brow + wr * 64 + m * 16 + lg * 4 + j;
        int c = bcol + wc * 64 + n * 16 + l15;
        if (OUTBF)
          ((unsigned short*)Cv)[(size_t)r * N + c] = f2bf(acc[m][n][j]);
        else
          ((float*)Cv)[(size_t)r * N + c] = acc[m][n][j];
      }
}

// ---------------------------------------------------------------------------
// RoPE in place on bf16 q [4096, 4096] and k [4096, 1024]; one u32 = one pair.
// ---------------------------------------------------------------------------
__global__ __launch_bounds__(256) void rope_bf16(
    unsigned* __restrict__ q, unsigned* __restrict__ k,
    const float* __restrict__ cosp, const float* __restrict__ sinp) {
  const int NQ = MROWS * (DD / 2);           // 8.39M q pairs
  const int NT = NQ + MROWS * (NKV * HDIM / 2);
  int stride = gridDim.x * blockDim.x;
  for (int p = blockIdx.x * blockDim.x + threadIdx.x; p < NT; p += stride) {
    bool isq = p < NQ;
    int pp = isq ? p : p - NQ;
    int row = isq ? (pp >> 11) : (pp >> 9);
    int hp  = isq ? (pp & 2047) : (pp & 511);
    int i = hp & 63, l = row & (LL - 1);
    float c = cosp[l * 64 + i], s = sinp[l * 64 + i];
    unsigned* ptr = isq ? (q + (size_t)row * 2048 + hp)
                        : (k + (size_t)row * 512 + hp);
    unsigned v = *ptr;
    float tr = bf2f((unsigned short)(v & 0xffff));
    float ti = bf2f((unsigned short)(v >> 16));
    *ptr = packbf2(tr * c - ti * s, tr * s + ti * c);
  }
}

// ---------------------------------------------------------------------------
// Flash causal GQA attention, bf16 MFMA. 2-PHASE DOUBLE-BUFFERED (T3-min+T14):
// per step: issue next-tile K gload_lds + V global->reg, compute current tile,
// then vmcnt-implicit V reg->LDS write + ONE barrier. Load latency hides under
// the ~1.5k-cycle compute phase instead of sitting on the critical path.
// Grid (L/64, B*H), 4 waves; wave w owns 16 q rows. KV tile = 64 keys.
// LDS 64KB (2 buffers) -> 2 blocks/CU; self-overlap replaces the missing TLP.
// ---------------------------------------------------------------------------
__global__ __launch_bounds__(256) void attn_mfma(
    const unsigned short* __restrict__ Qb, const unsigned short* __restrict__ Kb,
    const unsigned short* __restrict__ Vb, unsigned short* __restrict__ Ob) {
  __shared__ unsigned short Ks[2][64 * 128];  // [key][dim] 16-slot swz, 16KB ea
  __shared__ unsigned short Vt[2][128 * 64];  // [dim][key]  8-slot swz, 16KB ea
  const int tid = threadIdx.x;
  const int lane = tid & 63, w = tid >> 6;
  const int l15 = lane & 15, lg = lane >> 4;
  const int qt = (int)gridDim.x - 1 - (int)blockIdx.x;  // heavy blocks first
  const int bh = blockIdx.y;
  const int b = bh >> 5, h = bh & 31, kvh = h >> 2;
  const int qrel = w * 16 + l15;
  const size_t qrow = (size_t)(b * LL + qt * 64 + qrel);

  bf16x8 qf[4];
#pragma unroll
  for (int c = 0; c < 4; ++c)
    qf[c] = *(const bf16x8*)&Qb[qrow * DD + h * HDIM + c * 32 + lg * 8];

  f32x4 oacc[8];
#pragma unroll
  for (int d = 0; d < 8; ++d)
#pragma unroll
    for (int j = 0; j < 4; ++j) oacc[d][j] = 0.f;
  float mrun = -1e30f, lrun = 0.f;
  const float scale = 0.08838834764831845f;  // 1/sqrt(128)

  // --- staging helpers -----------------------------------------------------
  auto stageK = [&](int nb, int t) {  // K tile via global_load_lds, linear dest
#pragma unroll
    for (int i = 0; i < 4; ++i) {
      int idx = i * 256 + tid;
      int krow = idx >> 4, slot = idx & 15;
      gload_lds16(&Kb[(size_t)(b * LL + t * 64 + krow) * (NKV * HDIM) +
                      kvh * HDIM + ((slot ^ (krow & 15)) * 8)],
                  &Ks[nb][idx * 8]);
    }
  };
  auto loadV = [&](int t, u16x8* vreg) {  // V tile global -> regs (issue-early)
#pragma unroll
    for (int i = 0; i < 4; ++i) {
      int f = i * 256 + tid;
      int key = f & 63, d0 = (f >> 6) * 8;
      vreg[i] = *(const u16x8*)&Vb[(size_t)(b * LL + t * 64 + key) *
                                   (NKV * HDIM) + kvh * HDIM + d0];
    }
  };
  auto writeV = [&](int nb, const u16x8* vreg) {  // regs -> transposed LDS
#pragma unroll
    for (int i = 0; i < 4; ++i) {
      int f = i * 256 + tid;
      int key = f & 63, d0 = (f >> 6) * 8;
#pragma unroll
      for (int j = 0; j < 8; ++j) {
        int dim = d0 + j;
        Vt[nb][dim * 64 + (((key >> 3) ^ (dim & 7)) * 8) + (key & 7)] = vreg[i][j];
      }
    }
  };

  // --- per-tile compute ----------------------------------------------------
  auto compute = [&](int nb, bool boundary) {
    // S^T[64key][16q] = K * Q^T
    f32x4 sa[4];
    __builtin_amdgcn_s_setprio(1);
#pragma unroll
    for (int mb = 0; mb < 4; ++mb) {
#pragma unroll
      for (int j = 0; j < 4; ++j) sa[mb][j] = 0.f;
#pragma unroll
      for (int c = 0; c < 4; ++c) {
        int row = mb * 16 + l15;
        int phys = (c * 4 + lg) ^ l15;  // 16-slot swizzle
        bf16x8 kf = *(const bf16x8*)&Ks[nb][row * 128 + phys * 8];
        sa[mb] = MFMA16(kf, qf[c], sa[mb]);
      }
    }
    __builtin_amdgcn_s_setprio(0);

    // scale + causal mask (only boundary tile) -> online softmax
#pragma unroll
    for (int mb = 0; mb < 4; ++mb)
#pragma unroll
      for (int j = 0; j < 4; ++j) {
        float s = sa[mb][j] * scale;
        if (boundary && (mb * 16 + lg * 4 + j > qrel)) s = -1e30f;
        sa[mb][j] = s;
      }
    float vm = -1e30f;
#pragma unroll
    for (int mb = 0; mb < 4; ++mb)
#pragma unroll
      for (int j = 0; j < 4; ++j) vm = fmaxf(vm, sa[mb][j]);
    vm = fmaxf(vm, __shfl_xor(vm, 16));
    vm = fmaxf(vm, __shfl_xor(vm, 32));
    float mnew = fmaxf(mrun, vm);
    float corr = __expf(mrun - mnew);
    float psum = 0.f;
#pragma unroll
    for (int mb = 0; mb < 4; ++mb)
#pragma unroll
      for (int j = 0; j < 4; ++j) {
        float p = __expf(sa[mb][j] - mnew);
        sa[mb][j] = p;
        psum += p;
      }
    psum += __shfl_xor(psum, 16);
    psum += __shfl_xor(psum, 32);
    lrun = lrun * corr + psum;
    mrun = mnew;
#pragma unroll
    for (int d = 0; d < 8; ++d)
#pragma unroll
      for (int j = 0; j < 4; ++j) oacc[d][j] *= corr;

    // pack P to bf16 pairs: pk[mb][0]=(j0,j1), pk[mb][1]=(j2,j3)
    unsigned pk[4][2];
#pragma unroll
    for (int mb = 0; mb < 4; ++mb) {
      pk[mb][0] = packbf2(sa[mb][0], sa[mb][1]);
      pk[mb][1] = packbf2(sa[mb][2], sa[mb][3]);
    }

    // PV: O^T[128dim][16q] += V^T * P^T  (two K=32 halves)
#pragma unroll
    for (int kh = 0; kh < 2; ++kh) {
      unsigned pbu[4];
#pragma unroll
      for (int r = 0; r < 4; ++r) {
        int srcl = l15 + 16 * ((lg & 1) * 2 + (r >> 1));
        unsigned va = (unsigned)__shfl((int)pk[2 * kh][r & 1], srcl);
        unsigned vb = (unsigned)__shfl((int)pk[2 * kh + 1][r & 1], srcl);
        pbu[r] = (lane & 32) ? vb : va;
      }
      bf16x8 pb;
#pragma unroll
      for (int r = 0; r < 4; ++r) {
        pb[2 * r]     = (short)(pbu[r] & 0xffff);
        pb[2 * r + 1] = (short)(pbu[r] >> 16);
      }
      const int phys = ((kh * 4 + lg) ^ (l15 & 7));
      __builtin_amdgcn_s_setprio(1);
#pragma unroll
      for (int mbd = 0; mbd < 8; ++mbd) {
        int row = mbd * 16 + l15;
        bf16x8 vf = *(const bf16x8*)&Vt[nb][row * 64 + phys * 8];
        oacc[mbd] = MFMA16(vf, pb, oacc[mbd]);
      }
      __builtin_amdgcn_s_setprio(0);
    }
  };

  // --- 2-phase pipeline ----------------------------------------------------
  u16x8 vreg[4];
  stageK(0, 0);                 // prologue: tile 0 -> buf 0
  loadV(0, vreg);
  writeV(0, vreg);              // compiler inserts vmcnt wait for vreg
  __syncthreads();              // drains K gload_lds (vmcnt 0) + ds_writes

  int cur = 0;
  for (int t0 = 0; t0 < qt; ++t0) {
    stageK(cur ^ 1, t0 + 1);    // issue next-tile loads BEFORE compute
    loadV(t0 + 1, vreg);
    compute(cur, false);        // ~1.5k cycles hide the load latency
    writeV(cur ^ 1, vreg);      // write-late (T14)
    __syncthreads();            // single barrier per tile
    cur ^= 1;
  }
  compute(cur, true);           // boundary tile with causal mask

  // epilogue: O^T frag (dim=mbd*16+lg*4+j, q=l15) -> bf16 rows of attn buffer
  float inv = 1.f / lrun;
#pragma unroll
  for (int mbd = 0; mbd < 8; ++mbd)
#pragma unroll
    for (int j = 0; j < 4; j += 2) {
      int dim = mbd * 16 + lg * 4 + j;
      unsigned pk2 = packbf2(oacc[mbd][j] * inv, oacc[mbd][j + 1] * inv);
      *(unsigned*)&Ob[qrow * DD + h * HDIM + dim] = pk2;
    }
}

// ---------------------------------------------------------------------------
// Launch graph: cast(x) ; q,k,v GEMMs ; rope ; attn ; out GEMM
// ws (bytes): xb 32M | qbf 32M | kbf 8M | vbf 8M | attnbf 32M = 112 MB
// ---------------------------------------------------------------------------
extern "C" void kernel_launch(void* const* d_in, const int* in_sizes, int n_in,
                              void* d_out, int out_size, void* d_ws, size_t ws_size,
                              hipStream_t stream) {
  const float* x    = (const float*)d_in[0];
  const float* wq   = (const float*)d_in[1];
  const float* wk   = (const float*)d_in[2];
  const float* wv   = (const float*)d_in[3];
  const float* wo   = (const float*)d_in[4];
  const float* cosp = (const float*)d_in[5];
  const float* sinp = (const float*)d_in[6];
  float* out = (float*)d_out;

  unsigned short* xb     = (unsigned short*)d_ws;
  unsigned short* qbf    = xb + (size_t)MROWS * DD;
  unsigned short* kbf    = qbf + (size_t)MROWS * DD;
  unsigned short* vbf    = kbf + (size_t)MROWS * (NKV * HDIM);
  unsigned short* attnbf = vbf + (size_t)MROWS * (NKV * HDIM);

  dim3 blk(256);
  cast_f32_bf16<<<4096, blk, 0, stream>>>(x, xb, MROWS * DD);
  gemm_bt<true><<<dim3(DD / 128, MROWS / 128), blk, 0, stream>>>(
      xb, wq, qbf, MROWS, DD, DD);
  gemm_bt<true><<<dim3((NKV * HDIM) / 128, MROWS / 128), blk, 0, stream>>>(
      xb, wk, kbf, MROWS, NKV * HDIM, DD);
  gemm_bt<true><<<dim3((NKV * HDIM) / 128, MROWS / 128), blk, 0, stream>>>(
      xb, wv, vbf, MROWS, NKV * HDIM, DD);
  rope_bf16<<<8192, blk, 0, stream>>>((unsigned*)qbf, (unsigned*)kbf, cosp, sinp);
  attn_mfma<<<dim3(LL / 64, BB * HH), blk, 0, stream>>>(qbf, kbf, vbf, attnbf);
  gemm_bt<false><<<dim3(DD / 128, MROWS / 128), blk, 0, stream>>>(
      attnbf, wo, out, MROWS, DD, DD);
}